// Round 4
// baseline (242.201 us; speedup 1.0000x reference)
//
#include <hip/hip_runtime.h>
#include <hip/hip_cooperative_groups.h>
#include <math.h>

namespace cg = cooperative_groups;

constexpr int   NUM_RES = 2048;
constexpr float CUTOFF  = 10.0f;
constexpr int   NGRAPH  = 64;

// ws layout (ints): [0,4096) res_flags, [4096] mut_flag,
//                   [4097,4162) starts_a (65), [4162,4227) starts_b (65)
constexpr int WS_FLAGS    = 0;
constexpr int WS_MUTFLAG  = 4096;
constexpr int WS_STARTS_A = 4097;
constexpr int WS_STARTS_B = 4162;

__device__ __forceinline__ int lower_bound_i32(const int* __restrict__ arr, int n, int key) {
    int lo = 0, hi = n;
    while (lo < hi) {
        int mid = (lo + hi) >> 1;
        if (arr[mid] < key) lo = mid + 1; else hi = mid;
    }
    return lo;
}

// Single cooperative kernel, 1024 blocks x 256 threads (4 blocks/CU -> all
// co-resident; launch_bounds caps VGPR so cooperative launch can't fail on
// occupancy). Three phases separated by grid.sync():
//   A: zero residue flags + mut flag, build per-graph start tables
//   C: mut dtype detect + quarter-wave (16-lane) nearest-neighbor argmin
//   E: per-atom mask write
__global__ void __launch_bounds__(256, 4)
fused_kernel(const float* __restrict__ pos_a, const float* __restrict__ pos_b,
             const int* __restrict__ n2g_a, const int* __restrict__ n2g_b,
             const int* __restrict__ a2r_a, const int* __restrict__ a2r_b,
             const unsigned char* __restrict__ mut,
             int Na, int Nb,
             float* __restrict__ out,       // [0,Ntot) mask, [Ntot,2*Ntot) dists
             int* __restrict__ ws)
{
    cg::grid_group grid = cg::this_grid();
    const int tid      = blockIdx.x * blockDim.x + threadIdx.x;
    const int nthreads = gridDim.x * blockDim.x;   // 262144
    const int Ntot     = Na + Nb;

    // ---- Phase A: init ----
    for (int i = tid; i < 2 * NUM_RES + 1; i += nthreads) ws[WS_FLAGS + i] = 0;
    if (tid >= 8192 && tid < 8192 + (NGRAPH + 1))
        ws[WS_STARTS_A + (tid - 8192)] = lower_bound_i32(n2g_a, Na, tid - 8192);
    if (tid >= 8320 && tid < 8320 + (NGRAPH + 1))
        ws[WS_STARTS_B + (tid - 8320)] = lower_bound_i32(n2g_b, Nb, tid - 8320);

    grid.sync();

    // ---- Phase C: mut dtype detect (flag now safely zeroed) ----
    // if int32 with 0/1 payloads, every byte at i%4!=0 is 0; if uint8,
    // ~1% of bytes are 1 so some i%4!=0 byte is nonzero.
    {
        int acc = 0;
        for (int i = tid; i < Ntot; i += nthreads)
            if ((i & 3) != 0 && mut[i] != 0) acc = 1;
        if (acc) atomicOr(&ws[WS_MUTFLAG], 1);
    }

    // ---- Phase C: nearest. 16-lane group per atom, 2 atoms per group ----
    {
        const int sub     = tid & 15;
        const int gid     = tid >> 4;
        const int ngroups = nthreads >> 4;     // 16384

        for (int a = gid; a < Ntot; a += ngroups) {
            const float* ps; const float* po;
            const int* n2g_s; const int* a2r; const int* starts_o;
            int i, side;
            if (a < Na) {
                side = 0; i = a;
                ps = pos_a; po = pos_b; n2g_s = n2g_a; a2r = a2r_a;
                starts_o = ws + WS_STARTS_B;
            } else {
                side = 1; i = a - Na;
                ps = pos_b; po = pos_a; n2g_s = n2g_b; a2r = a2r_b;
                starts_o = ws + WS_STARTS_A;
            }

            float x = ps[3 * i + 0];
            float y = ps[3 * i + 1];
            float z = ps[3 * i + 2];
            int g  = n2g_s[i];
            int r  = a2r[i];
            int lo = starts_o[g];
            int hi = starts_o[g + 1];

            // lane-local scan (ascending j per lane; strict < = first occurrence)
            int   best   = 0;
            float bestd2 = INFINITY;
            #pragma unroll 4
            for (int j = lo + sub; j < hi; j += 16) {
                float dx = x - po[3 * j + 0];
                float dy = y - po[3 * j + 1];
                float dz = z - po[3 * j + 2];
                float d2 = dx * dx + dy * dy + dz * dz;
                if (d2 < bestd2) { bestd2 = d2; best = j; }
            }

            // cross-lane argmin within 16-lane segment:
            // smaller d2 wins; tie -> smaller index (first occurrence)
            for (int off = 8; off >= 1; off >>= 1) {
                float od2 = __shfl_down(bestd2, off, 16);
                int   oj  = __shfl_down(best,   off, 16);
                if (od2 < bestd2 || (od2 == bestd2 && oj < best)) {
                    bestd2 = od2; best = oj;
                }
            }

            if (sub == 0) {
                // recompute the norm at the argmin exactly like the reference
                float dx = x - po[3 * best + 0];
                float dy = y - po[3 * best + 1];
                float dz = z - po[3 * best + 2];
                float dist = sqrtf(dx * dx + dy * dy + dz * dz);
                out[Ntot + a] = dist;
                if (dist < CUTOFF) {
                    // benign idempotent race: everyone writes 1
                    ws[WS_FLAGS + side * NUM_RES + r] = 1;
                }
            }
        }
    }

    grid.sync();

    // ---- Phase E: mask ----
    {
        const int mutflag = ws[WS_MUTFLAG];
        for (int t = tid; t < Ntot; t += nthreads) {
            int side = (t < Na) ? 0 : 1;
            int i    = (t < Na) ? t : t - Na;
            int r    = side ? a2r_b[i] : a2r_a[i];
            int iface = ws[WS_FLAGS + side * NUM_RES + r];
            int m = mutflag ? (mut[t] != 0)
                            : (((const int*)mut)[t] != 0);
            out[t] = (iface || m) ? 1.0f : 0.0f;
        }
    }
}

extern "C" void kernel_launch(void* const* d_in, const int* in_sizes, int n_in,
                              void* d_out, int out_size, void* d_ws, size_t ws_size,
                              hipStream_t stream) {
    const float* pos_a = (const float*)d_in[0];
    const float* pos_b = (const float*)d_in[1];
    const int*   n2g_a = (const int*)d_in[2];
    const int*   n2g_b = (const int*)d_in[3];
    const int*   a2r_a = (const int*)d_in[4];
    const int*   a2r_b = (const int*)d_in[5];
    const unsigned char* mut = (const unsigned char*)d_in[6];

    int Na = in_sizes[0] / 3;
    int Nb = in_sizes[1] / 3;

    float* out = (float*)d_out;   // [0, Ntot) mask, [Ntot, 2*Ntot) dists
    int* ws = (int*)d_ws;

    void* args[] = {
        (void*)&pos_a, (void*)&pos_b,
        (void*)&n2g_a, (void*)&n2g_b,
        (void*)&a2r_a, (void*)&a2r_b,
        (void*)&mut,
        (void*)&Na, (void*)&Nb,
        (void*)&out, (void*)&ws
    };
    hipLaunchCooperativeKernel((void*)fused_kernel, dim3(1024), dim3(256),
                               args, 0, stream);
}

// Round 5
// 78.813 us; speedup vs baseline: 3.0731x; 3.0731x over previous
//
#include <hip/hip_runtime.h>
#include <math.h>

constexpr int   NUM_RES = 2048;
constexpr float CUTOFF  = 10.0f;
constexpr int   NGRAPH  = 64;

__device__ __forceinline__ int lower_bound_i32(const int* __restrict__ arr, int n, int key) {
    int lo = 0, hi = n;
    while (lo < hi) {
        int mid = (lo + hi) >> 1;
        if (arr[mid] < key) lo = mid + 1; else hi = mid;
    }
    return lo;
}

// ws layout (ints): [0,4096) res_flags, [4096] mut_flag,
//                   [4097,4162) starts_a (65), [4162,4227) starts_b (65)
constexpr int WS_FLAGS   = 0;
constexpr int WS_MUTFLAG = 4096;
constexpr int WS_STARTS_A = 4097;
constexpr int WS_STARTS_B = 4162;

// One kernel: zero residue flags, detect is_mutation storage width
// (uint8 vs int32), and build per-graph start-offset tables for both sides.
__global__ void init_kernel(const unsigned char* __restrict__ mut, int Ntot,
                            const int* __restrict__ n2g_a, int Na,
                            const int* __restrict__ n2g_b, int Nb,
                            int* __restrict__ ws) {
    int tid = blockIdx.x * blockDim.x + threadIdx.x;
    int nthreads = blockDim.x * gridDim.x;

    // zero flags + mut_flag
    for (int i = tid; i < 2 * NUM_RES + 1; i += nthreads) ws[WS_FLAGS + i] = 0;

    // graph range tables: g in [0, NGRAPH] inclusive (65 entries each side)
    if (tid >= 8192 && tid < 8192 + (NGRAPH + 1))
        ws[WS_STARTS_A + (tid - 8192)] = lower_bound_i32(n2g_a, Na, tid - 8192);
    if (tid >= 8320 && tid < 8320 + (NGRAPH + 1))
        ws[WS_STARTS_B + (tid - 8320)] = lower_bound_i32(n2g_b, Nb, tid - 8320);

    // dtype detect: if int32 with 0/1 payloads, every byte at i%4!=0 is 0;
    // if uint8, ~1% of bytes are 1 so some i%4!=0 byte is nonzero.
    int acc = 0;
    for (int i = tid; i < Ntot; i += nthreads)
        if ((i & 3) != 0 && mut[i] != 0) acc = 1;
    if (acc) atomicOr(&ws[WS_MUTFLAG], 1);
}

// Quarter-wave (16 lanes) per atom, 4 atoms per wave. Each 16-lane group
// scans the opposite-side graph range (stride 16), then a 4-step segment
// shuffle-reduce of the (d2, idx) argmin. 2048 blocks * 4 waves = 32
// waves/CU -> whole grid co-resident in a single batch.
__global__ void __launch_bounds__(256, 8)
nearest_kernel(const float* __restrict__ pos_a,
               const float* __restrict__ pos_b,
               const int* __restrict__ n2g_a,
               const int* __restrict__ n2g_b,
               const int* __restrict__ a2r_a,
               const int* __restrict__ a2r_b,
               int Na, int Nb,
               float* __restrict__ out_dists,
               int* __restrict__ ws) {
    int tid  = blockIdx.x * blockDim.x + threadIdx.x;
    int sub  = tid & 15;        // lane within 16-lane group
    int atom = tid >> 4;        // global atom id over both sides
    int Ntot = Na + Nb;
    if (atom >= Ntot) return;

    const float* ps; const float* po;
    const int* n2g_s; const int* a2r; const int* starts_o;
    int i, side;
    if (atom < Na) {
        side = 0; i = atom;
        ps = pos_a; po = pos_b; n2g_s = n2g_a; a2r = a2r_a;
        starts_o = ws + WS_STARTS_B;
    } else {
        side = 1; i = atom - Na;
        ps = pos_b; po = pos_a; n2g_s = n2g_b; a2r = a2r_b;
        starts_o = ws + WS_STARTS_A;
    }

    float x = ps[3 * i + 0];
    float y = ps[3 * i + 1];
    float z = ps[3 * i + 2];
    int g  = n2g_s[i];
    int r  = a2r[i];            // hoisted: independent, coalesced
    int lo = starts_o[g];
    int hi = starts_o[g + 1];

    // lane-local scan (ascending j per lane; strict < = first occurrence)
    int   best   = 0;
    float bestd2 = INFINITY;
    #pragma unroll 4
    for (int j = lo + sub; j < hi; j += 16) {
        float dx = x - po[3 * j + 0];
        float dy = y - po[3 * j + 1];
        float dz = z - po[3 * j + 2];
        float d2 = dx * dx + dy * dy + dz * dz;
        if (d2 < bestd2) { bestd2 = d2; best = j; }
    }

    // cross-lane argmin within the 16-lane segment:
    // smaller d2 wins; tie -> smaller index (first occurrence)
    for (int off = 8; off >= 1; off >>= 1) {
        float od2 = __shfl_down(bestd2, off, 16);
        int   oj  = __shfl_down(best,   off, 16);
        if (od2 < bestd2 || (od2 == bestd2 && oj < best)) {
            bestd2 = od2; best = oj;
        }
    }

    if (sub == 0) {
        // recompute the norm at the argmin exactly like the reference
        float dx = x - po[3 * best + 0];
        float dy = y - po[3 * best + 1];
        float dz = z - po[3 * best + 2];
        float dist = sqrtf(dx * dx + dy * dy + dz * dz);
        out_dists[atom] = dist;
        if (dist < CUTOFF) {
            // benign idempotent race: everyone writes 1
            ws[WS_FLAGS + side * NUM_RES + r] = 1;
        }
    }
}

__global__ void mask_kernel(const void* __restrict__ mut,
                            const int* __restrict__ a2r_a,
                            const int* __restrict__ a2r_b,
                            int Na, int Nb,
                            const int* __restrict__ ws,
                            float* __restrict__ out_mask) {
    int tid = blockIdx.x * blockDim.x + threadIdx.x;
    int Ntot = Na + Nb;
    if (tid >= Ntot) return;

    int side = (tid < Na) ? 0 : 1;
    int i    = (tid < Na) ? tid : tid - Na;
    int r    = side ? a2r_b[i] : a2r_a[i];
    int iface = ws[WS_FLAGS + side * NUM_RES + r];

    int m;
    if (ws[WS_MUTFLAG]) {
        m = ((const unsigned char*)mut)[tid] != 0;
    } else {
        m = ((const int*)mut)[tid] != 0;
    }
    out_mask[tid] = (iface || m) ? 1.0f : 0.0f;
}

extern "C" void kernel_launch(void* const* d_in, const int* in_sizes, int n_in,
                              void* d_out, int out_size, void* d_ws, size_t ws_size,
                              hipStream_t stream) {
    const float* pos_a = (const float*)d_in[0];
    const float* pos_b = (const float*)d_in[1];
    const int*   n2g_a = (const int*)d_in[2];
    const int*   n2g_b = (const int*)d_in[3];
    const int*   a2r_a = (const int*)d_in[4];
    const int*   a2r_b = (const int*)d_in[5];
    const void*  mut   = d_in[6];

    int Na = in_sizes[0] / 3;
    int Nb = in_sizes[1] / 3;
    int Ntot = Na + Nb;

    float* out = (float*)d_out;   // [0, Ntot) mask, [Ntot, 2*Ntot) dists
    int* ws = (int*)d_ws;

    init_kernel<<<64, 256, 0, stream>>>((const unsigned char*)mut, Ntot,
                                        n2g_a, Na, n2g_b, Nb, ws);

    // 16 lanes per atom; 256-thread blocks = 16 atoms/block
    int nblocks = (Ntot * 16 + 255) / 256;
    nearest_kernel<<<nblocks, 256, 0, stream>>>(pos_a, pos_b, n2g_a, n2g_b,
                                                a2r_a, a2r_b, Na, Nb,
                                                out + Ntot, ws);

    mask_kernel<<<(Ntot + 255) / 256, 256, 0, stream>>>(mut, a2r_a, a2r_b,
                                                        Na, Nb, ws, out);
}